// Round 2
// baseline (344.466 us; speedup 1.0000x reference)
//
#include <hip/hip_runtime.h>
#include <stdint.h>

#define TDIM 512
#define FDIM 1024
#define NTOT 33554432.0f   // 64*512*1024
#define EPS  1e-5f

typedef unsigned short ushort_t;
typedef unsigned short ushort4_t __attribute__((ext_vector_type(4)));
typedef short short8 __attribute__((ext_vector_type(8)));
typedef float floatx4 __attribute__((ext_vector_type(4)));

__device__ __forceinline__ ushort_t f2bf(float f) {
    union { float f; uint32_t u; } v; v.f = f;
    uint32_t r = (v.u + 0x7fffu + ((v.u >> 16) & 1u)) >> 16;
    return (ushort_t)r;
}

// async global->LDS, 16B per lane; LDS dest is wave-uniform base + lane*16
__device__ __forceinline__ void async16(const ushort_t* g, ushort_t* l) {
    __builtin_amdgcn_global_load_lds(
        (const __attribute__((address_space(1))) void*)g,
        (__attribute__((address_space(3))) void*)l, 16, 0, 0);
}

// Chunked tile layout (the GEMM's exact LDS image, 8KB per (tile, kt)):
//   tile(b,ft,kt) base = ((b*8+ft)*16 + kt) * 4096 ushorts
//   element (k,n): offset (q*128 + n)*8 + e,  q=(k&31)>>3, e=k&7, n=col&127

// ---------------------------------------------------------------------------
// Kernel 1: pass over x: per-block partial sum/sumsq (no atomics) + write
// xT in CHUNKED bf16 layout. Tile 64(t) x 128(f). grid = 4096 blocks.
// ---------------------------------------------------------------------------
__global__ __launch_bounds__(256) void k_stats_transpose(
    const float* __restrict__ x, ushort_t* __restrict__ xTC,
    float2* __restrict__ partials)
{
    __shared__ ushort_t tile[64 * 128];   // [t][f], 16KB
    __shared__ float red[8];

    int tid = threadIdx.x, bid = blockIdx.x;
    int b  = bid >> 6;
    int t0 = ((bid >> 3) & 7) << 6;
    int ft = bid & 7;
    int f0 = ft << 7;

    int r8 = tid >> 5, c8 = tid & 31;
    const float* xb = x + ((size_t)(b * TDIM + t0) * FDIM) + f0;

    float4 v[8];
#pragma unroll
    for (int p = 0; p < 8; ++p)
        v[p] = *(const float4*)(xb + (size_t)(p * 8 + r8) * FDIM + c8 * 4);

    float s = 0.f, q = 0.f;
#pragma unroll
    for (int p = 0; p < 8; ++p) {
        float4 t = v[p];
        s += t.x + t.y + t.z + t.w;
        q += t.x * t.x + t.y * t.y + t.z * t.z + t.w * t.w;
        ushort4_t pk;
        pk[0] = f2bf(t.x); pk[1] = f2bf(t.y); pk[2] = f2bf(t.z); pk[3] = f2bf(t.w);
        *(ushort4_t*)&tile[(p * 8 + r8) * 128 + c8 * 4] = pk;   // b64, conflict-free
    }

#pragma unroll
    for (int off = 32; off > 0; off >>= 1) {
        s += __shfl_down(s, off, 64);
        q += __shfl_down(q, off, 64);
    }
    int lane = tid & 63, w = tid >> 6;
    if (lane == 0) { red[w] = s; red[4 + w] = q; }
    __syncthreads();   // covers tile writes AND red[]
    if (tid == 0) {
        partials[bid] = make_float2(red[0] + red[1] + red[2] + red[3],
                                    red[4] + red[5] + red[6] + red[7]);
    }

    // phase 2: gather-transpose to chunked layout; stores are lane-contiguous
    // 16B -> 1KB/wave coalesced. LDS u16 gathers are 2-way (free).
    int fl = tid & 127, hf = tid >> 7;
    size_t base = ((size_t)((b * 8 + ft) * 16) + (t0 >> 5) + hf) * 4096;
#pragma unroll
    for (int qq = 0; qq < 4; ++qq) {
        int tr = hf * 32 + qq * 8;
        uint32_t w0 = (uint32_t)tile[(tr + 0) * 128 + fl] | ((uint32_t)tile[(tr + 1) * 128 + fl] << 16);
        uint32_t w1 = (uint32_t)tile[(tr + 2) * 128 + fl] | ((uint32_t)tile[(tr + 3) * 128 + fl] << 16);
        uint32_t w2 = (uint32_t)tile[(tr + 4) * 128 + fl] | ((uint32_t)tile[(tr + 5) * 128 + fl] << 16);
        uint32_t w3 = (uint32_t)tile[(tr + 6) * 128 + fl] | ((uint32_t)tile[(tr + 7) * 128 + fl] << 16);
        uint4 o = make_uint4(w0, w1, w2, w3);
        *(uint4*)&xTC[base + (size_t)(qq * 128 + fl) * 8] = o;
    }
}

// ---------------------------------------------------------------------------
// Kernel 2: cast W to bf16 in CHUNKED layout + per-row sum.
// ---------------------------------------------------------------------------
__global__ __launch_bounds__(256) void k_wcast(
    const float* __restrict__ W, ushort_t* __restrict__ WbC,
    float* __restrict__ rowsumW)
{
    __shared__ float red[4];
    int u = blockIdx.x, tid = threadIdx.x;
    float2 lv = *(const float2*)(W + (size_t)u * 512 + 2 * tid);

    int mt = u >> 7, m = u & 127;
    int kt = tid >> 4;
    int qq = (tid & 15) >> 2;
    int e  = 2 * (tid & 3);
    size_t off = ((size_t)(mt * 16 + kt)) * 4096 + (size_t)(qq * 128 + m) * 8 + e;
    uint32_t pk = (uint32_t)f2bf(lv.x) | ((uint32_t)f2bf(lv.y) << 16);
    *(uint32_t*)&WbC[off] = pk;

    float s = lv.x + lv.y;
#pragma unroll
    for (int off2 = 32; off2 > 0; off2 >>= 1) s += __shfl_down(s, off2, 64);
    int lane = tid & 63, w = tid >> 6;
    if (lane == 0) red[w] = s;
    __syncthreads();
    if (tid == 0) rowsumW[u] = red[0] + red[1] + red[2] + red[3];
}

// ---------------------------------------------------------------------------
// Kernel 3: single-block final reduce: partials -> a; d[u] = c*rowsumW + bias.
// ---------------------------------------------------------------------------
__global__ __launch_bounds__(256) void k_reduce(
    const float2* __restrict__ partials, const float* __restrict__ rowsumW,
    const float* __restrict__ bias, const float* __restrict__ gamma,
    const float* __restrict__ beta, float* __restrict__ stats,
    float* __restrict__ d)
{
    __shared__ float red[8];
    __shared__ float sac[2];
    int tid = threadIdx.x;
    float s = 0.f, q = 0.f;
#pragma unroll
    for (int i = 0; i < 16; ++i) {
        float2 p = partials[i * 256 + tid];
        s += p.x; q += p.y;
    }
#pragma unroll
    for (int off = 32; off > 0; off >>= 1) {
        s += __shfl_down(s, off, 64);
        q += __shfl_down(q, off, 64);
    }
    int lane = tid & 63, w = tid >> 6;
    if (lane == 0) { red[w] = s; red[4 + w] = q; }
    __syncthreads();
    if (tid == 0) {
        float S = red[0] + red[1] + red[2] + red[3];
        float Q = red[4] + red[5] + red[6] + red[7];
        float mean = S * (1.f / NTOT);
        float var  = Q * (1.f / NTOT) - mean * mean;
        float a    = gamma[0] * rsqrtf(var + EPS);
        float c    = beta[0] - mean * a;
        stats[0] = a;
        sac[0] = a; sac[1] = c;
    }
    __syncthreads();
    float c = sac[1];
    d[tid]       = c * rowsumW[tid]       + bias[tid];
    d[tid + 256] = c * rowsumW[tid + 256] + bias[tid + 256];
}

// ---------------------------------------------------------------------------
// Kernel 4: GEMM v3.
//   * A (WbC, 512KB, L2-resident) is loaded DIRECTLY global->VGPR per iter:
//     the chunked fragment address is 4x256B coalesced per wave. Removes A's
//     LDS write+read (halves LDS traffic) and halves the stage-drain volume.
//   * B stays double-buffered via global_load_lds (2 loads/thread/iter).
//   * 1-D grid with XCD-bijective swizzle: the 4 mt-blocks sharing one xTC
//     B-tile get identical bid%8 (same XCD under round-robin) and adjacent
//     dispatch slots -> B reuse is served by that XCD's L2, not L3.
//   * LDS back to 17408B (2x8KB B + epilogue ldsC alias) -> 8 blocks/CU cap.
// ---------------------------------------------------------------------------
__global__ __launch_bounds__(256) void k_gemm(
    const ushort_t* __restrict__ WbC, const ushort_t* __restrict__ xTC,
    const float* __restrict__ x, const float* __restrict__ d,
    const float* __restrict__ stats, float* __restrict__ out)
{
    __shared__ ulong smem_raw[2176];             // 17408 B
    ushort_t* lds  = (ushort_t*)smem_raw;        // B dbuf: 2 x 4096 ushorts
    float*    ldsC = (float*)smem_raw;           // 32*132*4 = 16896 B (epilogue)

    int tid = threadIdx.x;
    int w = tid >> 6, lane = tid & 63;

    // XCD-bijective decode: hb = xcd + 8*(mt + 4*slot); nt = slot*8 + xcd
    int hb   = blockIdx.x;          // 0..2047
    int xcd  = hb & 7;
    int rr   = hb >> 3;             // 0..255
    int mt   = rr & 3;              // 0..3   (u tile)
    int nt   = ((rr >> 2) << 3) + xcd;  // 0..511 (b, f tile)
    int b = nt >> 3, ft = nt & 7;

    int wr = w >> 1, wc = w & 1;
    int l15 = lane & 15, q = lane >> 4;

    const ushort_t* Abase = WbC + (size_t)mt * 16 * 4096;
    const ushort_t* Bbase = xTC + (size_t)(b * 8 + ft) * 16 * 4096 + tid * 8;

    // per-thread constant part of the A-fragment offset (ushorts)
    int aoff = (q * 128 + wr * 64 + l15) * 8;

    floatx4 acc[4][4] = {};

    // prologue: stage B(kt=0) into buffer 0
    async16(Bbase,        &lds[tid * 8]);
    async16(Bbase + 2048, &lds[2048 + tid * 8]);
    __syncthreads();

    for (int kt = 0; kt < 16; ++kt) {
        int cur = (kt & 1) << 12;            // 0 or 4096 ushorts
        int nxt = 4096 - cur;
        if (kt < 15) {                       // issue next B tile's stage first
            const ushort_t* Bg = Bbase + (kt + 1) * 4096;
            async16(Bg,        &lds[nxt + tid * 8]);
            async16(Bg + 2048, &lds[nxt + 2048 + tid * 8]);
        }

        // A fragments straight from L2 (no LDS round-trip)
        const ushort_t* Ag = Abase + kt * 4096 + aoff;
        short8 af[4], bfr[4];
#pragma unroll
        for (int i = 0; i < 4; ++i)
            af[i] = *(const short8*)&Ag[i * 128];          // i*16 rows * 8
#pragma unroll
        for (int j = 0; j < 4; ++j) {
            int n = wc * 64 + j * 16 + l15;
            bfr[j] = *(const short8*)&lds[cur + (q * 128 + n) * 8];
        }
#pragma unroll
        for (int i = 0; i < 4; ++i)
#pragma unroll
            for (int j = 0; j < 4; ++j)
                acc[i][j] = __builtin_amdgcn_mfma_f32_16x16x32_bf16(
                    af[i], bfr[j], acc[i][j], 0, 0, 0);

        __syncthreads();   // drains B stage (and any A prefetch) after compute
    }

    // epilogue: 4 passes of 32 rows through LDS (stride 132 -> 2-way only)
    float a = stats[0];
    int row = tid >> 3, cs = (tid & 7) * 16;
#pragma unroll
    for (int p = 0; p < 4; ++p) {
        if (wr == (p >> 1)) {
#pragma unroll
            for (int ii = 0; ii < 2; ++ii) {
                int i = (p & 1) * 2 + ii;
                int rl0 = i * 16 + q * 4 - (p & 1) * 32;
#pragma unroll
                for (int j = 0; j < 4; ++j) {
                    int col = wc * 64 + j * 16 + l15;
#pragma unroll
                    for (int r = 0; r < 4; ++r)
                        ldsC[(rl0 + r) * 132 + col] = acc[i][j][r];
                }
            }
        }
        __syncthreads();
        int tg = mt * 128 + p * 32 + row;
        float dt = d[tg];
        size_t gbase = ((size_t)b * TDIM + tg) * FDIM + ft * 128 + cs;
        const float* xr = x + gbase;
        float* orow = out + gbase;
#pragma unroll
        for (int k4 = 0; k4 < 4; ++k4) {
            float4 xv = *(const float4*)(xr + k4 * 4);
            float4 cv = *(const float4*)&ldsC[row * 132 + cs + k4 * 4];
            float4 o;
            o.x = xv.x + fmaxf(a * cv.x + dt, 0.f);
            o.y = xv.y + fmaxf(a * cv.y + dt, 0.f);
            o.z = xv.z + fmaxf(a * cv.z + dt, 0.f);
            o.w = xv.w + fmaxf(a * cv.w + dt, 0.f);
            *(float4*)(orow + k4 * 4) = o;
        }
        __syncthreads();
    }
}

// ---------------------------------------------------------------------------
extern "C" void kernel_launch(void* const* d_in, const int* in_sizes, int n_in,
                              void* d_out, int out_size, void* d_ws, size_t ws_size,
                              hipStream_t stream) {
    const float* x     = (const float*)d_in[0];
    const float* W     = (const float*)d_in[1];
    const float* bias  = (const float*)d_in[2];
    const float* gamma = (const float*)d_in[3];
    const float* beta  = (const float*)d_in[4];
    float* out = (float*)d_out;

    char* ws = (char*)d_ws;
    float*    stats    = (float*)ws;                   // 8 B
    float*    dvec     = (float*)(ws + 1024);          // 2 KB
    float*    rowsumW  = (float*)(ws + 4096);          // 2 KB
    float2*   partials = (float2*)(ws + 8192);         // 32 KB
    ushort_t* WbC      = (ushort_t*)(ws + (64 << 10)); // 512 KB
    ushort_t* xTC      = (ushort_t*)(ws + (1 << 20));  // 64 MB

    k_stats_transpose<<<4096, 256, 0, stream>>>(x, xTC, partials);
    k_wcast<<<512, 256, 0, stream>>>(W, WbC, rowsumW);
    k_reduce<<<1, 256, 0, stream>>>(partials, rowsumW, bias, gamma, beta, stats, dvec);
    k_gemm<<<2048, 256, 0, stream>>>(WbC, xTC, x, dvec, stats, out);
}

// Round 3
// 315.518 us; speedup vs baseline: 1.0917x; 1.0917x over previous
//
#include <hip/hip_runtime.h>
#include <stdint.h>

#define TDIM 512
#define FDIM 1024
#define NTOT 33554432.0f   // 64*512*1024
#define EPS  1e-5f

typedef unsigned short ushort_t;
typedef unsigned short ushort4_t __attribute__((ext_vector_type(4)));
typedef short short8 __attribute__((ext_vector_type(8)));
typedef float floatx4 __attribute__((ext_vector_type(4)));

__device__ __forceinline__ ushort_t f2bf(float f) {
    union { float f; uint32_t u; } v; v.f = f;
    uint32_t r = (v.u + 0x7fffu + ((v.u >> 16) & 1u)) >> 16;
    return (ushort_t)r;
}

// async global->LDS, 16B per lane; LDS dest is wave-uniform base + lane*16
__device__ __forceinline__ void async16(const ushort_t* g, ushort_t* l) {
    __builtin_amdgcn_global_load_lds(
        (const __attribute__((address_space(1))) void*)g,
        (__attribute__((address_space(3))) void*)l, 16, 0, 0);
}

// Chunked tile layout (the GEMM's exact LDS image, 8KB per (tile, kt)):
//   tile(b,ft,kt) base = ((b*8+ft)*16 + kt) * 4096 ushorts
//   element (k,n): offset (q*128 + n)*8 + e,  q=(k&31)>>3, e=k&7, n=col&127

// ---------------------------------------------------------------------------
// Kernel 1: pass over x: per-block partial sum/sumsq (no atomics) + write
// xT in CHUNKED bf16 layout. Tile 64(t) x 128(f). grid = 4096 blocks.
// ---------------------------------------------------------------------------
__global__ __launch_bounds__(256) void k_stats_transpose(
    const float* __restrict__ x, ushort_t* __restrict__ xTC,
    float2* __restrict__ partials)
{
    __shared__ ushort_t tile[64 * 128];   // [t][f], 16KB
    __shared__ float red[8];

    int tid = threadIdx.x, bid = blockIdx.x;
    int b  = bid >> 6;
    int t0 = ((bid >> 3) & 7) << 6;
    int ft = bid & 7;
    int f0 = ft << 7;

    int r8 = tid >> 5, c8 = tid & 31;
    const float* xb = x + ((size_t)(b * TDIM + t0) * FDIM) + f0;

    float4 v[8];
#pragma unroll
    for (int p = 0; p < 8; ++p)
        v[p] = *(const float4*)(xb + (size_t)(p * 8 + r8) * FDIM + c8 * 4);

    float s = 0.f, q = 0.f;
#pragma unroll
    for (int p = 0; p < 8; ++p) {
        float4 t = v[p];
        s += t.x + t.y + t.z + t.w;
        q += t.x * t.x + t.y * t.y + t.z * t.z + t.w * t.w;
        ushort4_t pk;
        pk[0] = f2bf(t.x); pk[1] = f2bf(t.y); pk[2] = f2bf(t.z); pk[3] = f2bf(t.w);
        *(ushort4_t*)&tile[(p * 8 + r8) * 128 + c8 * 4] = pk;   // b64, conflict-free
    }

#pragma unroll
    for (int off = 32; off > 0; off >>= 1) {
        s += __shfl_down(s, off, 64);
        q += __shfl_down(q, off, 64);
    }
    int lane = tid & 63, w = tid >> 6;
    if (lane == 0) { red[w] = s; red[4 + w] = q; }
    __syncthreads();   // covers tile writes AND red[]
    if (tid == 0) {
        partials[bid] = make_float2(red[0] + red[1] + red[2] + red[3],
                                    red[4] + red[5] + red[6] + red[7]);
    }

    // phase 2: gather-transpose to chunked layout; stores are lane-contiguous
    // 16B -> 1KB/wave coalesced. LDS u16 gathers are 2-way (free).
    int fl = tid & 127, hf = tid >> 7;
    size_t base = ((size_t)((b * 8 + ft) * 16) + (t0 >> 5) + hf) * 4096;
#pragma unroll
    for (int qq = 0; qq < 4; ++qq) {
        int tr = hf * 32 + qq * 8;
        uint32_t w0 = (uint32_t)tile[(tr + 0) * 128 + fl] | ((uint32_t)tile[(tr + 1) * 128 + fl] << 16);
        uint32_t w1 = (uint32_t)tile[(tr + 2) * 128 + fl] | ((uint32_t)tile[(tr + 3) * 128 + fl] << 16);
        uint32_t w2 = (uint32_t)tile[(tr + 4) * 128 + fl] | ((uint32_t)tile[(tr + 5) * 128 + fl] << 16);
        uint32_t w3 = (uint32_t)tile[(tr + 6) * 128 + fl] | ((uint32_t)tile[(tr + 7) * 128 + fl] << 16);
        uint4 o = make_uint4(w0, w1, w2, w3);
        *(uint4*)&xTC[base + (size_t)(qq * 128 + fl) * 8] = o;
    }
}

// ---------------------------------------------------------------------------
// Kernel 2: cast W to bf16 in CHUNKED layout + per-row sum.
// ---------------------------------------------------------------------------
__global__ __launch_bounds__(256) void k_wcast(
    const float* __restrict__ W, ushort_t* __restrict__ WbC,
    float* __restrict__ rowsumW)
{
    __shared__ float red[4];
    int u = blockIdx.x, tid = threadIdx.x;
    float2 lv = *(const float2*)(W + (size_t)u * 512 + 2 * tid);

    int mt = u >> 7, m = u & 127;
    int kt = tid >> 4;
    int qq = (tid & 15) >> 2;
    int e  = 2 * (tid & 3);
    size_t off = ((size_t)(mt * 16 + kt)) * 4096 + (size_t)(qq * 128 + m) * 8 + e;
    uint32_t pk = (uint32_t)f2bf(lv.x) | ((uint32_t)f2bf(lv.y) << 16);
    *(uint32_t*)&WbC[off] = pk;

    float s = lv.x + lv.y;
#pragma unroll
    for (int off2 = 32; off2 > 0; off2 >>= 1) s += __shfl_down(s, off2, 64);
    int lane = tid & 63, w = tid >> 6;
    if (lane == 0) red[w] = s;
    __syncthreads();
    if (tid == 0) rowsumW[u] = red[0] + red[1] + red[2] + red[3];
}

// ---------------------------------------------------------------------------
// Kernel 3: single-block final reduce: partials -> a; d[u] = c*rowsumW + bias.
// ---------------------------------------------------------------------------
__global__ __launch_bounds__(256) void k_reduce(
    const float2* __restrict__ partials, const float* __restrict__ rowsumW,
    const float* __restrict__ bias, const float* __restrict__ gamma,
    const float* __restrict__ beta, float* __restrict__ stats,
    float* __restrict__ d)
{
    __shared__ float red[8];
    __shared__ float sac[2];
    int tid = threadIdx.x;
    float s = 0.f, q = 0.f;
#pragma unroll
    for (int i = 0; i < 16; ++i) {
        float2 p = partials[i * 256 + tid];
        s += p.x; q += p.y;
    }
#pragma unroll
    for (int off = 32; off > 0; off >>= 1) {
        s += __shfl_down(s, off, 64);
        q += __shfl_down(q, off, 64);
    }
    int lane = tid & 63, w = tid >> 6;
    if (lane == 0) { red[w] = s; red[4 + w] = q; }
    __syncthreads();
    if (tid == 0) {
        float S = red[0] + red[1] + red[2] + red[3];
        float Q = red[4] + red[5] + red[6] + red[7];
        float mean = S * (1.f / NTOT);
        float var  = Q * (1.f / NTOT) - mean * mean;
        float a    = gamma[0] * rsqrtf(var + EPS);
        float c    = beta[0] - mean * a;
        stats[0] = a;
        sac[0] = a; sac[1] = c;
    }
    __syncthreads();
    float c = sac[1];
    d[tid]       = c * rowsumW[tid]       + bias[tid];
    d[tid + 256] = c * rowsumW[tid + 256] + bias[tid + 256];
}

// ---------------------------------------------------------------------------
// Kernel 4: GEMM v4 — T3+T4 counted-vmcnt pipeline (guide m218/m230 pattern).
//   * A and B both staged via global_load_lds into a 3-SLOT LDS ring (48KB):
//     iter kt issues stage(kt+2), then `s_waitcnt vmcnt(8)` (waits ONLY for
//     stage(kt); the 8 loads of kt+1/kt+2 stay in flight across the barrier),
//     raw s_barrier, ds_read frags, lgkmcnt(0), raw s_barrier (WAR guard for
//     next iter's overwrite of this slot), 16 MFMA. No vmcnt(0) in the loop;
//     drain ladder 8->4->0 in the last two iterations.
//   * XCD-bijective grid swizzle kept from v3 (proven FETCH 199->107 MB).
// ---------------------------------------------------------------------------
__global__ __launch_bounds__(256) void k_gemm(
    const ushort_t* __restrict__ WbC, const ushort_t* __restrict__ xTC,
    const float* __restrict__ x, const float* __restrict__ d,
    const float* __restrict__ stats, float* __restrict__ out)
{
    __shared__ ulong smem_raw[6144];             // 49152 B: 3 slots x (A8K+B8K)
    ushort_t* lds  = (ushort_t*)smem_raw;
    float*    ldsC = (float*)smem_raw;           // 32*132*4 = 16896 B (epilogue)

    int tid = threadIdx.x;
    int w = tid >> 6, lane = tid & 63;

    // XCD-bijective decode: hb = xcd + 8*(mt + 4*slot); nt = slot*8 + xcd
    int hb   = blockIdx.x;          // 0..2047
    int xcd  = hb & 7;
    int rr   = hb >> 3;             // 0..255
    int mt   = rr & 3;              // 0..3   (u tile)
    int nt   = ((rr >> 2) << 3) + xcd;  // 0..511 (b, f tile)
    int b = nt >> 3, ft = nt & 7;

    int wr = w >> 1, wc = w & 1;
    int l15 = lane & 15, q = lane >> 4;

    const ushort_t* Ab = WbC + (size_t)mt * 16 * 4096 + tid * 8;
    const ushort_t* Bb = xTC + (size_t)(b * 8 + ft) * 16 * 4096 + tid * 8;

    floatx4 acc[4][4] = {};

    // stage K-tile kt into ring slot s (4 x 16B gload_lds per thread)
    auto stage = [&](int kt, int s) {
        const ushort_t* Ag = Ab + kt * 4096;
        const ushort_t* Bg = Bb + kt * 4096;
        ushort_t* ls = lds + s * 8192;
        async16(Ag,        &ls[tid * 8]);
        async16(Ag + 2048, &ls[2048 + tid * 8]);
        async16(Bg,        &ls[4096 + tid * 8]);
        async16(Bg + 2048, &ls[4096 + 2048 + tid * 8]);
    };

    // prologue: 2-deep prefetch
    stage(0, 0);
    stage(1, 1);

#pragma unroll
    for (int kt = 0; kt < 16; ++kt) {
        if (kt < 14) {
            stage(kt + 2, (kt + 2) % 3);
            asm volatile("s_waitcnt vmcnt(8)" ::: "memory");   // stage(kt) done
        } else if (kt == 14) {
            asm volatile("s_waitcnt vmcnt(4)" ::: "memory");   // stage(14) done
        } else {
            asm volatile("s_waitcnt vmcnt(0)" ::: "memory");   // stage(15) done
        }
        __builtin_amdgcn_s_barrier();        // slot kt ready for ALL waves

        const ushort_t* cA = lds + (kt % 3) * 8192;
        const ushort_t* cB = cA + 4096;
        short8 af[4], bfr[4];
#pragma unroll
        for (int i = 0; i < 4; ++i) {
            int m = wr * 64 + i * 16 + l15;
            af[i] = *(const short8*)&cA[(q * 128 + m) * 8];
        }
#pragma unroll
        for (int j = 0; j < 4; ++j) {
            int n = wc * 64 + j * 16 + l15;
            bfr[j] = *(const short8*)&cB[(q * 128 + n) * 8];
        }
        // reads must complete before any wave's next-iter stage overwrites slot
        asm volatile("s_waitcnt lgkmcnt(0)" ::: "memory");
        __builtin_amdgcn_s_barrier();

#pragma unroll
        for (int i = 0; i < 4; ++i)
#pragma unroll
            for (int j = 0; j < 4; ++j)
                acc[i][j] = __builtin_amdgcn_mfma_f32_16x16x32_bf16(
                    af[i], bfr[j], acc[i][j], 0, 0, 0);
    }

    __syncthreads();   // full drain before ldsC aliases the ring

    // epilogue: 4 passes of 32 rows through LDS (stride 132 -> 2-way only)
    float a = stats[0];
    int row = tid >> 3, cs = (tid & 7) * 16;
#pragma unroll
    for (int p = 0; p < 4; ++p) {
        if (wr == (p >> 1)) {
#pragma unroll
            for (int ii = 0; ii < 2; ++ii) {
                int i = (p & 1) * 2 + ii;
                int rl0 = i * 16 + q * 4 - (p & 1) * 32;
#pragma unroll
                for (int j = 0; j < 4; ++j) {
                    int col = wc * 64 + j * 16 + l15;
#pragma unroll
                    for (int r = 0; r < 4; ++r)
                        ldsC[(rl0 + r) * 132 + col] = acc[i][j][r];
                }
            }
        }
        __syncthreads();
        int tg = mt * 128 + p * 32 + row;
        float dt = d[tg];
        size_t gbase = ((size_t)b * TDIM + tg) * FDIM + ft * 128 + cs;
        const float* xr = x + gbase;
        float* orow = out + gbase;
#pragma unroll
        for (int k4 = 0; k4 < 4; ++k4) {
            float4 xv = *(const float4*)(xr + k4 * 4);
            float4 cv = *(const float4*)&ldsC[row * 132 + cs + k4 * 4];
            float4 o;
            o.x = xv.x + fmaxf(a * cv.x + dt, 0.f);
            o.y = xv.y + fmaxf(a * cv.y + dt, 0.f);
            o.z = xv.z + fmaxf(a * cv.z + dt, 0.f);
            o.w = xv.w + fmaxf(a * cv.w + dt, 0.f);
            *(float4*)(orow + k4 * 4) = o;
        }
        __syncthreads();
    }
}

// ---------------------------------------------------------------------------
extern "C" void kernel_launch(void* const* d_in, const int* in_sizes, int n_in,
                              void* d_out, int out_size, void* d_ws, size_t ws_size,
                              hipStream_t stream) {
    const float* x     = (const float*)d_in[0];
    const float* W     = (const float*)d_in[1];
    const float* bias  = (const float*)d_in[2];
    const float* gamma = (const float*)d_in[3];
    const float* beta  = (const float*)d_in[4];
    float* out = (float*)d_out;

    char* ws = (char*)d_ws;
    float*    stats    = (float*)ws;                   // 8 B
    float*    dvec     = (float*)(ws + 1024);          // 2 KB
    float*    rowsumW  = (float*)(ws + 4096);          // 2 KB
    float2*   partials = (float2*)(ws + 8192);         // 32 KB
    ushort_t* WbC      = (ushort_t*)(ws + (64 << 10)); // 512 KB
    ushort_t* xTC      = (ushort_t*)(ws + (1 << 20));  // 64 MB

    k_stats_transpose<<<4096, 256, 0, stream>>>(x, xTC, partials);
    k_wcast<<<512, 256, 0, stream>>>(W, WbC, rowsumW);
    k_reduce<<<1, 256, 0, stream>>>(partials, rowsumW, bias, gamma, beta, stats, dvec);
    k_gemm<<<2048, 256, 0, stream>>>(WbC, xTC, x, dvec, stats, out);
}